// Round 3
// baseline (1057.845 us; speedup 1.0000x reference)
//
#include <hip/hip_runtime.h>
#include <stdint.h>

#define NN 128
#define BB 4096
#define HH 32

typedef float f4 __attribute__((ext_vector_type(4)));

// Pre-pass: bit-pack A transposed. bit d of word (b,node) = (A[b][d][node] != 0).
// float4-vectorized: each thread owns 4 consecutive nodes, walks all 128 rows d.
__global__ __launch_bounds__(256) void pack_bits(const float* __restrict__ A,
                                                 ulonglong2* __restrict__ bitsT) {
    const int tid = blockIdx.x * 256 + threadIdx.x;   // BB*32 threads total
    const int b   = tid >> 5;
    const int ng  = (tid & 31) << 2;                  // this thread's 4 nodes
    const float* Ab = A + (size_t)b * (NN * NN) + ng;
    unsigned long long w0[4] = {0ull, 0ull, 0ull, 0ull};
    unsigned long long w1[4] = {0ull, 0ull, 0ull, 0ull};
#pragma unroll 8
    for (int d = 0; d < 64; ++d) {
        f4 v = __builtin_nontemporal_load((const f4*)(Ab + (size_t)d * NN));
        const unsigned long long bit = 1ull << d;
        if (v[0] != 0.f) w0[0] |= bit;
        if (v[1] != 0.f) w0[1] |= bit;
        if (v[2] != 0.f) w0[2] |= bit;
        if (v[3] != 0.f) w0[3] |= bit;
    }
#pragma unroll 8
    for (int d = 0; d < 64; ++d) {
        f4 v = __builtin_nontemporal_load((const f4*)(Ab + (size_t)(d + 64) * NN));
        const unsigned long long bit = 1ull << d;
        if (v[0] != 0.f) w1[0] |= bit;
        if (v[1] != 0.f) w1[1] |= bit;
        if (v[2] != 0.f) w1[2] |= bit;
        if (v[3] != 0.f) w1[3] |= bit;
    }
    ulonglong2* o = bitsT + b * NN + ng;
#pragma unroll
    for (int i = 0; i < 4; ++i) {
        ulonglong2 r; r.x = w0[i]; r.y = w1[i];
        o[i] = r;
    }
}

// Pull one sparse entry from the (m0 ++ m1) mask pair. Pure SALU + 2 readlane.
// After both masks are empty: d=64, v=0 (harmless dummy row, fma adds 0).
#define PULL(dO, vO)                                                        \
    {                                                                       \
        const bool _s0 = (m0 != 0ull);                                      \
        const unsigned long long _m = _s0 ? m0 : m1;                        \
        const bool _ok = (_m != 0ull);                                      \
        int _d = (int)__builtin_ctzll(_m | 0x8000000000000000ull);          \
        _d = _ok ? _d : 0;                                                  \
        const float _va = __int_as_float(__builtin_amdgcn_readlane(         \
            __float_as_int(out0), _d));                                     \
        const float _vb = __int_as_float(__builtin_amdgcn_readlane(         \
            __float_as_int(out1), _d));                                     \
        const float _v = _s0 ? _va : _vb;                                   \
        vO = _ok ? _v : 0.f;                                                \
        dO = _s0 ? _d : (_d + 64);                                          \
        const unsigned long long _mn = _m & (_m - 1ull);                    \
        m0 = _s0 ? _mn : m0;                                                \
        m1 = _s0 ? m1 : _mn;                                                \
    }

// One wave (64 lanes) per batch element. outputs: out0 (d=lane), out1 (d=lane+64).
// v4: no LDS at all. Ballot masks live in SGPRs; entry indices extracted with
// SALU bit-walk, values broadcast via v_readlane, W1-row loads issued in
// width-4 groups pipelined 2 deep (group B's loads in flight while group A's
// FMAs run). Removes the per-entry LDS->global dependent-load chain that
// round-2 counters showed to be ~2000 stall cycles/step.
__global__ __launch_bounds__(64) void cond_mlp(
    const float* __restrict__ x, const float* __restrict__ u,
    const float* __restrict__ W1, const float* __restrict__ b1,
    const float* __restrict__ W2, const float* __restrict__ b2,
    const int* __restrict__ order, const int* __restrict__ do_idxs,
    const ulonglong2* __restrict__ bitsT, float* __restrict__ out)
{
    const int b = blockIdx.x;
    const int lane = threadIdx.x;
    const int j = lane & 31;       // hidden index

    const float ub = u[b];
    const int dob = do_idxs[b];
    float out0 = (dob == lane) ? ub : 0.f;
    float out1 = (dob == lane + 64) ? ub : 0.f;

    const int* ord = order + b * NN;
    const ulonglong2* bb = bitsT + (size_t)b * NN;

    int node = ord[0];
    ulonglong2 bits = bb[node];

    for (int t = 0; t < NN; ++t) {
        // ---- prefetch next step's uniform data (no vmcnt(0) drains) ----
        const int node_n = (t < NN - 1) ? ord[t + 1] : 0;
        const ulonglong2 bits_n = bb[node_n];

        const float* Wn = W1 + (size_t)node * (NN + 1) * HH;
        // epilogue loads issued early (consumed after the gather)
        const float w2v  = W2[node * HH + j];
        const float b1v  = b1[node * HH + j];
        const float xv   = x[b * NN + node];
        const float b2v  = b2[node];
        const float w1xv = Wn[NN * HH + j];   // W1 row 128 (the x input row)

        // ---- force mask words into SGPRs (readlane needs uniform index,
        //      and the whole bit-walk must stay SALU) ----
        const unsigned int bxl = __builtin_amdgcn_readfirstlane((unsigned int)bits.x);
        const unsigned int bxh = __builtin_amdgcn_readfirstlane((unsigned int)(bits.x >> 32));
        const unsigned int byl = __builtin_amdgcn_readfirstlane((unsigned int)bits.y);
        const unsigned int byh = __builtin_amdgcn_readfirstlane((unsigned int)(bits.y >> 32));
        unsigned long long m0 = __ballot(out0 != 0.f) &
                                (((unsigned long long)bxh << 32) | bxl);
        unsigned long long m1 = __ballot(out1 != 0.f) &
                                (((unsigned long long)byh << 32) | byl);
        const int cnt = __popcll(m0) + __popcll(m1);

        // ---- sparse gather: SGPR bit-walk, width-4 groups, depth-2 pipe ----
        float acc = 0.f;
        const int G = (cnt + 3) >> 2;
        if (G) {
            int dA0, dA1, dA2, dA3, dB0, dB1, dB2, dB3;
            float vA0, vA1, vA2, vA3, vB0, vB1, vB2, vB3;
            float wA0, wA1, wA2, wA3, wB0, wB1, wB2, wB3;

            PULL(dA0, vA0) PULL(dA1, vA1) PULL(dA2, vA2) PULL(dA3, vA3)
            wA0 = Wn[(dA0 << 5) + j];
            wA1 = Wn[(dA1 << 5) + j];
            wA2 = Wn[(dA2 << 5) + j];
            wA3 = Wn[(dA3 << 5) + j];

            for (int g = 1; g < G; g += 2) {
                PULL(dB0, vB0) PULL(dB1, vB1) PULL(dB2, vB2) PULL(dB3, vB3)
                wB0 = Wn[(dB0 << 5) + j];
                wB1 = Wn[(dB1 << 5) + j];
                wB2 = Wn[(dB2 << 5) + j];
                wB3 = Wn[(dB3 << 5) + j];

                acc += vA0 * wA0; acc += vA1 * wA1;
                acc += vA2 * wA2; acc += vA3 * wA3;

                PULL(dA0, vA0) PULL(dA1, vA1) PULL(dA2, vA2) PULL(dA3, vA3)
                wA0 = Wn[(dA0 << 5) + j];
                wA1 = Wn[(dA1 << 5) + j];
                wA2 = Wn[(dA2 << 5) + j];
                wA3 = Wn[(dA3 << 5) + j];

                acc += vB0 * wB0; acc += vB1 * wB1;
                acc += vB2 * wB2; acc += vB3 * wB3;
            }
            // drain the last issued A group (dummy-padded groups add 0)
            acc += vA0 * wA0; acc += vA1 * wA1;
            acc += vA2 * wA2; acc += vA3 * wA3;
        }

        acc += xv * w1xv;                      // the x input row (row 128)
        acc += b1v;
        const float hv = (acc > 0.f) ? acc : 0.01f * acc;   // leaky_relu

        // H -> 1 reduction over the 32 j-lanes: 4 DPP hops + one xor16
        // (correctness HW-validated rounds 1-2)
        float p = hv * w2v;
        p += __int_as_float(__builtin_amdgcn_update_dpp(
                 0, __float_as_int(p), 0xB1, 0xF, 0xF, true));   // quad_perm xor1
        p += __int_as_float(__builtin_amdgcn_update_dpp(
                 0, __float_as_int(p), 0x4E, 0xF, 0xF, true));   // quad_perm xor2
        p += __int_as_float(__builtin_amdgcn_update_dpp(
                 0, __float_as_int(p), 0x141, 0xF, 0xF, true));  // row_half_mirror
        p += __int_as_float(__builtin_amdgcn_update_dpp(
                 0, __float_as_int(p), 0x140, 0xF, 0xF, true));  // row_mirror
        p += __shfl_xor(p, 16);
        const float outv = p + b2v;

        // ---- state update (skip if this is the do-intervention node) ----
        if (dob != node && lane == (node & 63)) {
            if (node < 64) out0 = outv; else out1 = outv;
        }
        node = node_n;
        bits = bits_n;
    }

    out[b * NN + lane] = out0;
    out[b * NN + 64 + lane] = out1;
}

extern "C" void kernel_launch(void* const* d_in, const int* in_sizes, int n_in,
                              void* d_out, int out_size, void* d_ws, size_t ws_size,
                              hipStream_t stream) {
    const float* x   = (const float*)d_in[0];
    const float* A   = (const float*)d_in[1];
    const float* u   = (const float*)d_in[2];
    const float* W1  = (const float*)d_in[3];
    const float* b1  = (const float*)d_in[4];
    const float* W2  = (const float*)d_in[5];
    const float* b2  = (const float*)d_in[6];
    const int* order = (const int*)d_in[7];
    const int* dox   = (const int*)d_in[8];

    ulonglong2* bitsT = (ulonglong2*)d_ws;  // needs 4096*128*16 B = 8 MB

    pack_bits<<<(BB * 32) / 256, 256, 0, stream>>>(A, bitsT);
    cond_mlp<<<BB, 64, 0, stream>>>(x, u, W1, b1, W2, b2, order, dox,
                                    bitsT, (float*)d_out);
}

// Round 4
// 544.171 us; speedup vs baseline: 1.9440x; 1.9440x over previous
//
#include <hip/hip_runtime.h>
#include <stdint.h>

#define NN 128
#define BB 4096
#define HH 32

typedef float f4 __attribute__((ext_vector_type(4)));

// Pre-pass: bit-pack A transposed. bit d of word (b,node) = (A[b][d][node] != 0).
// float4-vectorized: each thread owns 4 consecutive nodes, walks all 128 rows d.
__global__ __launch_bounds__(256) void pack_bits(const float* __restrict__ A,
                                                 ulonglong2* __restrict__ bitsT) {
    const int tid = blockIdx.x * 256 + threadIdx.x;   // BB*32 threads total
    const int b   = tid >> 5;
    const int ng  = (tid & 31) << 2;                  // this thread's 4 nodes
    const float* Ab = A + (size_t)b * (NN * NN) + ng;
    unsigned long long w0[4] = {0ull, 0ull, 0ull, 0ull};
    unsigned long long w1[4] = {0ull, 0ull, 0ull, 0ull};
#pragma unroll 8
    for (int d = 0; d < 64; ++d) {
        f4 v = __builtin_nontemporal_load((const f4*)(Ab + (size_t)d * NN));
        const unsigned long long bit = 1ull << d;
        if (v[0] != 0.f) w0[0] |= bit;
        if (v[1] != 0.f) w0[1] |= bit;
        if (v[2] != 0.f) w0[2] |= bit;
        if (v[3] != 0.f) w0[3] |= bit;
    }
#pragma unroll 8
    for (int d = 0; d < 64; ++d) {
        f4 v = __builtin_nontemporal_load((const f4*)(Ab + (size_t)(d + 64) * NN));
        const unsigned long long bit = 1ull << d;
        if (v[0] != 0.f) w1[0] |= bit;
        if (v[1] != 0.f) w1[1] |= bit;
        if (v[2] != 0.f) w1[2] |= bit;
        if (v[3] != 0.f) w1[3] |= bit;
    }
    ulonglong2* o = bitsT + b * NN + ng;
#pragma unroll
    for (int i = 0; i < 4; ++i) {
        ulonglong2 r; r.x = w0[i]; r.y = w1[i];
        o[i] = r;
    }
}

// prefix-popcount of 64-bit mask below this lane (canonical mbcnt idiom)
__device__ __forceinline__ int mbcnt64(unsigned long long m) {
    return __builtin_amdgcn_mbcnt_hi((unsigned int)(m >> 32),
           __builtin_amdgcn_mbcnt_lo((unsigned int)m, 0));
}

// One wave (64 lanes) per batch element. outputs: out0 (d=lane), out1 (d=lane+64).
// v5: round-2 LDS compaction structure, with two structural fixes:
//  (a) STATIC gather blocks (16 entries/lane, fully unrolled) instead of a
//      runtime-trip loop -> all LDS reads issue at once, W-loads pipeline.
//  (b) scalar nz-bitmask replaces ballot; the just-computed node is routed
//      around the LDS (fresh term: outv_prev * W1[node][node_prev][j]),
//      so LDS values are >=1 step stale -> the cross-step serial chain is
//      only outv_prev -> one cndmask+FMA, not epilogue->ds_write->read->load.
//      (nz marks "ever computed or do-node"; a nz bit with value 0.0
//       contributes 0*W -> semantically identical to the reference.)
__global__ __launch_bounds__(64, 4) void cond_mlp(
    const float* __restrict__ x, const float* __restrict__ u,
    const float* __restrict__ W1, const float* __restrict__ b1,
    const float* __restrict__ W2, const float* __restrict__ b2,
    const int* __restrict__ order, const int* __restrict__ do_idxs,
    const ulonglong2* __restrict__ bitsT, float* __restrict__ out)
{
    const int b = blockIdx.x;
    const int lane = threadIdx.x;
    const int j = lane & 31;       // hidden index
    const int half = lane >> 5;    // which k-stream this lane serves

    __shared__ float2 ent[132];    // compacted (value, d*HH as int-bits) list

    const float ub = u[b];
    const int dob = __builtin_amdgcn_readfirstlane(do_idxs[b]);
    float out0 = (dob == lane) ? ub : 0.f;
    float out1 = (dob == lane + 64) ? ub : 0.f;

    // scalar nonzero-candidate masks (SGPR): init = do-node only
    unsigned long long nz0 = (dob >= 0 && dob < 64) ? (1ull << dob) : 0ull;
    unsigned long long nz1 = (dob >= 64) ? (1ull << (dob - 64)) : 0ull;

    const int* ord = order + b * NN;
    const ulonglong2* bb = bitsT + (size_t)b * NN;

    const unsigned long long lanebit = 1ull << lane;
    const float fidx0 = __int_as_float(lane << 5);          // d*HH pre-shifted
    const float fidx1 = __int_as_float((lane + 64) << 5);

    int node = __builtin_amdgcn_readfirstlane(ord[0]);
    ulonglong2 bits = bb[node];

    int node_prev = 0;          // valid only when t > 0
    float outv_prev = 0.f;

    for (int t = 0; t < NN; ++t) {
        const bool have_prev = (t > 0);
        // ---- prefetch next step's uniform data (stays in flight) ----
        const int node_n = (t < NN - 1)
            ? __builtin_amdgcn_readfirstlane(ord[t + 1]) : 0;
        const ulonglong2 bits_n = bb[node_n];

        const float* Wn = W1 + (size_t)node * (NN + 1) * HH;
        // epilogue + fresh-path loads issued early
        const float w2v  = W2[node * HH + j];
        const float b1v  = b1[node * HH + j];
        const float xv   = x[b * NN + node];
        const float b2v  = b2[node];
        const float w1xv = Wn[NN * HH + j];                // W1 row 128 (x input)
        const int   frow = (have_prev ? node_prev : 0) << 5;
        const float wfr  = Wn[frow + j];                   // fresh-path W row

        // ---- force mask words scalar; masks exclude node_prev (fresh path) ----
        const unsigned int bxl = __builtin_amdgcn_readfirstlane((unsigned int)bits.x);
        const unsigned int bxh = __builtin_amdgcn_readfirstlane((unsigned int)(bits.x >> 32));
        const unsigned int byl = __builtin_amdgcn_readfirstlane((unsigned int)bits.y);
        const unsigned int byh = __builtin_amdgcn_readfirstlane((unsigned int)(bits.y >> 32));
        const unsigned long long bw0 = ((unsigned long long)bxh << 32) | bxl;
        const unsigned long long bw1 = ((unsigned long long)byh << 32) | byl;
        const unsigned long long m0 = nz0 & bw0;
        const unsigned long long m1 = nz1 & bw1;
        const int c0 = __popcll(m0);
        const int cnt = c0 + __popcll(m1);
        const int cnt4 = (cnt + 3) & ~3;

        // ---- compaction writes (values are state t-2: node_prev excluded) ----
        const int p0 = mbcnt64(m0);
        if (m0 & lanebit) ent[p0] = make_float2(out0, fidx0);
        const int p1 = c0 + mbcnt64(m1);
        if (m1 & lanebit) ent[p1] = make_float2(out1, fidx1);
        // zero-pad up to the static-block boundary actually used
        const int top = (cnt4 <= 32) ? 32 : ((cnt4 <= 64) ? 64 : cnt4);
        const int pp = cnt + lane;
        if (pp < top) ent[pp] = make_float2(0.f, __int_as_float(0));

        // ---- apply pending update (after writes; slack = one full step) ----
        if (have_prev && dob != node_prev && lane == (node_prev & 63)) {
            if (node_prev < 64) out0 = outv_prev; else out1 = outv_prev;
        }
        if (have_prev) {
            if (node_prev < 64) nz0 |= 1ull << node_prev;
            else                nz1 |= 1ull << (node_prev - 64);
        }

        // single wave: LDS visibility only — no vmcnt drain
        asm volatile("s_waitcnt lgkmcnt(0)" ::: "memory");

        // ---- static gather block A: entries 0..31 (16 per lane) ----
        float acc;
        {
            float2 e[16];
#pragma unroll
            for (int i = 0; i < 16; ++i) e[i] = ent[2 * i + half];
            float w[16];
#pragma unroll
            for (int i = 0; i < 16; ++i) w[i] = Wn[__float_as_int(e[i].y) + j];
            float a0 = 0.f, a1 = 0.f, a2 = 0.f, a3 = 0.f;
#pragma unroll
            for (int i = 0; i < 16; i += 4) {
                a0 += e[i].x     * w[i];
                a1 += e[i + 1].x * w[i + 1];
                a2 += e[i + 2].x * w[i + 2];
                a3 += e[i + 3].x * w[i + 3];
            }
            acc = (a0 + a1) + (a2 + a3);
        }
        // ---- static gather block B: entries 32..63 (late steps only) ----
        if (cnt4 > 32) {
            float2 e[16];
#pragma unroll
            for (int i = 0; i < 16; ++i) e[i] = ent[32 + 2 * i + half];
            float w[16];
#pragma unroll
            for (int i = 0; i < 16; ++i) w[i] = Wn[__float_as_int(e[i].y) + j];
            float a0 = 0.f, a1 = 0.f, a2 = 0.f, a3 = 0.f;
#pragma unroll
            for (int i = 0; i < 16; i += 4) {
                a0 += e[i].x     * w[i];
                a1 += e[i + 1].x * w[i + 1];
                a2 += e[i + 2].x * w[i + 2];
                a3 += e[i + 3].x * w[i + 3];
            }
            acc += (a0 + a1) + (a2 + a3);
        }
        // ---- guard loop (cnt > 64: ~never at 0.3 density, kept for safety) ----
        if (cnt4 > 64) {
            for (int k = 64; k < cnt4; k += 4) {
                float2 eA = ent[k + half];
                float2 eB = ent[k + 2 + half];
                acc += eA.x * Wn[__float_as_int(eA.y) + j];
                acc += eB.x * Wn[__float_as_int(eB.y) + j];
            }
        }

        // merge the two k-streams, then add once-per-step terms
        float accT = acc + __shfl_xor(acc, 32);
        // fresh term: the node computed last step (only tight cross-step dep)
        const bool fc = have_prev && (dob != node_prev) &&
            (((node_prev < 64) ? (bw0 >> node_prev) : (bw1 >> (node_prev - 64))) & 1ull);
        accT += (fc ? outv_prev : 0.f) * wfr;
        accT += xv * w1xv;
        accT += b1v;
        const float hv = (accT > 0.f) ? accT : 0.01f * accT;   // leaky_relu

        // H -> 1 reduction over 32 j-lanes: 4 DPP hops + one xor16 (HW-validated)
        float p = hv * w2v;
        p += __int_as_float(__builtin_amdgcn_update_dpp(
                 0, __float_as_int(p), 0xB1, 0xF, 0xF, true));   // quad_perm xor1
        p += __int_as_float(__builtin_amdgcn_update_dpp(
                 0, __float_as_int(p), 0x4E, 0xF, 0xF, true));   // quad_perm xor2
        p += __int_as_float(__builtin_amdgcn_update_dpp(
                 0, __float_as_int(p), 0x141, 0xF, 0xF, true));  // row_half_mirror
        p += __int_as_float(__builtin_amdgcn_update_dpp(
                 0, __float_as_int(p), 0x140, 0xF, 0xF, true));  // row_mirror
        p += __shfl_xor(p, 16);
        const float outv = p + b2v;

        // defer the state update to next step (fresh path covers step t+1)
        outv_prev = outv;
        node_prev = node;
        node = node_n;
        bits = bits_n;
    }

    // apply the final pending update
    if (dob != node_prev && lane == (node_prev & 63)) {
        if (node_prev < 64) out0 = outv_prev; else out1 = outv_prev;
    }

    out[b * NN + lane] = out0;
    out[b * NN + 64 + lane] = out1;
}

extern "C" void kernel_launch(void* const* d_in, const int* in_sizes, int n_in,
                              void* d_out, int out_size, void* d_ws, size_t ws_size,
                              hipStream_t stream) {
    const float* x   = (const float*)d_in[0];
    const float* A   = (const float*)d_in[1];
    const float* u   = (const float*)d_in[2];
    const float* W1  = (const float*)d_in[3];
    const float* b1  = (const float*)d_in[4];
    const float* W2  = (const float*)d_in[5];
    const float* b2  = (const float*)d_in[6];
    const int* order = (const int*)d_in[7];
    const int* dox   = (const int*)d_in[8];

    ulonglong2* bitsT = (ulonglong2*)d_ws;  // needs 4096*128*16 B = 8 MB

    pack_bits<<<(BB * 32) / 256, 256, 0, stream>>>(A, bitsT);
    cond_mlp<<<BB, 64, 0, stream>>>(x, u, W1, b1, W2, b2, order, dox,
                                    bitsT, (float*)d_out);
}

// Round 5
// 528.633 us; speedup vs baseline: 2.0011x; 1.0294x over previous
//
#include <hip/hip_runtime.h>
#include <stdint.h>

#define NN 128
#define BB 4096
#define HH 32

typedef float f4 __attribute__((ext_vector_type(4)));

// Pre-pass: bit-pack A transposed. bit d of word (b,node) = (A[b][d][node] != 0).
__global__ __launch_bounds__(256) void pack_bits(const float* __restrict__ A,
                                                 ulonglong2* __restrict__ bitsT) {
    const int tid = blockIdx.x * 256 + threadIdx.x;   // BB*32 threads total
    const int b   = tid >> 5;
    const int ng  = (tid & 31) << 2;                  // this thread's 4 nodes
    const float* Ab = A + (size_t)b * (NN * NN) + ng;
    unsigned long long w0[4] = {0ull, 0ull, 0ull, 0ull};
    unsigned long long w1[4] = {0ull, 0ull, 0ull, 0ull};
#pragma unroll 8
    for (int d = 0; d < 64; ++d) {
        f4 v = __builtin_nontemporal_load((const f4*)(Ab + (size_t)d * NN));
        const unsigned long long bit = 1ull << d;
        if (v[0] != 0.f) w0[0] |= bit;
        if (v[1] != 0.f) w0[1] |= bit;
        if (v[2] != 0.f) w0[2] |= bit;
        if (v[3] != 0.f) w0[3] |= bit;
    }
#pragma unroll 8
    for (int d = 0; d < 64; ++d) {
        f4 v = __builtin_nontemporal_load((const f4*)(Ab + (size_t)(d + 64) * NN));
        const unsigned long long bit = 1ull << d;
        if (v[0] != 0.f) w1[0] |= bit;
        if (v[1] != 0.f) w1[1] |= bit;
        if (v[2] != 0.f) w1[2] |= bit;
        if (v[3] != 0.f) w1[3] |= bit;
    }
    ulonglong2* o = bitsT + b * NN + ng;
#pragma unroll
    for (int i = 0; i < 4; ++i) {
        ulonglong2 r; r.x = w0[i]; r.y = w1[i];
        o[i] = r;
    }
}

__device__ __forceinline__ int mbcnt64(unsigned long long m) {
    return __builtin_amdgcn_mbcnt_hi((unsigned int)(m >> 32),
           __builtin_amdgcn_mbcnt_lo((unsigned int)m, 0));
}
__device__ __forceinline__ unsigned long long rfl64(unsigned long long v) {
    unsigned int lo = __builtin_amdgcn_readfirstlane((unsigned int)v);
    unsigned int hi = __builtin_amdgcn_readfirstlane((unsigned int)(v >> 32));
    return ((unsigned long long)hi << 32) | lo;
}

// v6: one-full-step software pipeline. During step t:
//   - W rows for step t load at step TOP from register-prefetched entry indices
//     (addresses need no LDS wait) -> L2 latency hides under compaction work
//     + 3 other waves.
//   - compaction for t+1 is built from state <= t-1 (legal because r4's
//     verified fresh-path adds node_t's contribution at t+1 in-register),
//     written to the other LDS buffer, and its 16 entry ds_reads issue
//     immediately -> LDS latency spans nearly a whole step.
// The per-step serial chain (ds_write->read->Wload->FMA ~400cyc, = r4's
// 1536cyc/step all-4-waves-stalled residual) is thus spread across the
// step boundary instead of serializing inside it.
// STEP macro args: T=step, ECUR/ENXT = entry reg sets, BCUR/BNXT = LDS bufs.
#define STEP(T, ECUR, ENXT, BCUR, BNXT)                                      \
  {                                                                          \
    const float* Wn_cur = W1 + (size_t)node0 * ((NN + 1) * HH);              \
    /* 0: W loads for THIS step (addresses already in regs) */               \
    float wv[16];                                                            \
    _Pragma("unroll")                                                        \
    for (int i = 0; i < 16; ++i)                                             \
        wv[i] = Wn_cur[__float_as_int(ECUR[i].y) + j];                       \
    /* 1: apply pending update from step T-1 */                              \
    if ((T) > 0) {                                                           \
        if (dob != pend_node && lane == (pend_node & 63)) {                  \
            if (pend_node < 64) out0 = pend_val; else out1 = pend_val;       \
        }                                                                    \
        if (pend_node < 64) nz0 |= 1ull << pend_node;                        \
        else                nz1 |= 1ull << (pend_node - 64);                 \
    }                                                                        \
    /* 2: masks for step T+1 (node_T not yet in nz -> excluded) */           \
    const unsigned long long bw0n = rfl64(vbn.x);                            \
    const unsigned long long bw1n = rfl64(vbn.y);                            \
    const unsigned long long m0 = nz0 & bw0n;                                \
    const unsigned long long m1 = nz1 & bw1n;                                \
    const int c0n  = __popcll(m0);                                           \
    const int cntn = c0n + __popcll(m1);                                     \
    const int cnt4n = (cntn + 3) & ~3;                                       \
    /* 3: write compaction for T+1 into the other buffer */                  \
    {                                                                        \
        const int p0 = mbcnt64(m0);                                          \
        if (m0 & lanebit) entb[BNXT][p0] = make_float2(out0, fidx0);         \
        const int p1 = c0n + mbcnt64(m1);                                    \
        if (m1 & lanebit) entb[BNXT][p1] = make_float2(out1, fidx1);         \
        const int top = (cnt4n <= 32) ? 32 : cnt4n;                          \
        const int pp = cntn + lane;                                          \
        if (pp < top) entb[BNXT][pp] = make_float2(0.f, __int_as_float(0));  \
    }                                                                        \
    asm volatile("s_waitcnt lgkmcnt(0)" ::: "memory");                       \
    /* 4: entry ds_reads for T+1 (consumed next step) */                     \
    _Pragma("unroll")                                                        \
    for (int i = 0; i < 16; ++i) ENXT[i] = entb[BNXT][2 * i + half];         \
    /* 5: prefetch node_{T+2}, its bits, and T+1's epilogue scalars */       \
    const int node2 = ((T) + 2 < NN)                                         \
        ? __builtin_amdgcn_readfirstlane(ord[(T) + 2]) : 0;                  \
    const ulonglong2 vb2 = bb[node2];                                        \
    const float* Wn_nxt = W1 + (size_t)node1 * ((NN + 1) * HH);              \
    const float w2v_n  = W2[node1 * HH + j];                                 \
    const float b1v_n  = b1[node1 * HH + j];                                 \
    const float xv_n   = x[b * NN + node1];                                  \
    const float b2v_n  = b2[node1];                                          \
    const float w1xv_n = Wn_nxt[NN * HH + j];                                \
    const float wfr_n  = Wn_nxt[(node0 << 5) + j];                           \
    /* 6: FMAs for step T (entries + weights all in regs) */                 \
    float a0 = 0.f, a1 = 0.f, a2 = 0.f, a3 = 0.f;                            \
    _Pragma("unroll")                                                        \
    for (int i = 0; i < 16; i += 4) {                                        \
        a0 += ECUR[i].x     * wv[i];                                         \
        a1 += ECUR[i + 1].x * wv[i + 1];                                     \
        a2 += ECUR[i + 2].x * wv[i + 2];                                     \
        a3 += ECUR[i + 3].x * wv[i + 3];                                     \
    }                                                                        \
    float acc = (a0 + a1) + (a2 + a3);                                       \
    /* 7: overflow entries 32..cnt4 (late steps only, in-step chain) */      \
    if (cnt4_c > 32) {                                                       \
        for (int k = 32; k < cnt4_c; k += 4) {                               \
            float2 ea = entb[BCUR][k + half];                                \
            float2 eb = entb[BCUR][k + 2 + half];                            \
            acc += ea.x * Wn_cur[__float_as_int(ea.y) + j];                  \
            acc += eb.x * Wn_cur[__float_as_int(eb.y) + j];                  \
        }                                                                    \
    }                                                                        \
    /* 8: finish step T */                                                   \
    float accT = acc + __shfl_xor(acc, 32);                                  \
    const bool fc = ((T) > 0) && (dob != pend_node) &&                       \
        ((((pend_node < 64) ? (bw0c >> pend_node)                            \
                            : (bw1c >> (pend_node - 64)))) & 1ull);          \
    accT += (fc ? pend_val : 0.f) * wfr;                                     \
    accT += xv * w1xv;                                                       \
    accT += b1v;                                                             \
    const float hv = (accT > 0.f) ? accT : 0.01f * accT;                     \
    float pr = hv * w2v;                                                     \
    pr += __int_as_float(__builtin_amdgcn_update_dpp(                        \
             0, __float_as_int(pr), 0xB1, 0xF, 0xF, true));                  \
    pr += __int_as_float(__builtin_amdgcn_update_dpp(                        \
             0, __float_as_int(pr), 0x4E, 0xF, 0xF, true));                  \
    pr += __int_as_float(__builtin_amdgcn_update_dpp(                        \
             0, __float_as_int(pr), 0x141, 0xF, 0xF, true));                 \
    pr += __int_as_float(__builtin_amdgcn_update_dpp(                        \
             0, __float_as_int(pr), 0x140, 0xF, 0xF, true));                 \
    pr += __shfl_xor(pr, 16);                                                \
    const float outv = pr + b2v;                                             \
    pend_node = node0; pend_val = outv;                                      \
    /* 9: rotate */                                                          \
    node0 = node1; node1 = node2;                                            \
    bw0c = bw0n; bw1c = bw1n; vbn = vb2;                                     \
    w2v = w2v_n; b1v = b1v_n; xv = xv_n; b2v = b2v_n;                        \
    w1xv = w1xv_n; wfr = wfr_n;                                              \
    cnt4_c = cnt4n;                                                          \
  }

__global__ __launch_bounds__(64, 4) void cond_mlp(
    const float* __restrict__ x, const float* __restrict__ u,
    const float* __restrict__ W1, const float* __restrict__ b1,
    const float* __restrict__ W2, const float* __restrict__ b2,
    const int* __restrict__ order, const int* __restrict__ do_idxs,
    const ulonglong2* __restrict__ bitsT, float* __restrict__ out)
{
    const int b = blockIdx.x;
    const int lane = threadIdx.x;
    const int j = lane & 31;
    const int half = lane >> 5;

    __shared__ float2 entb[2][132];

    const float ub = u[b];
    const int dob = __builtin_amdgcn_readfirstlane(do_idxs[b]);
    float out0 = (dob == lane) ? ub : 0.f;
    float out1 = (dob == lane + 64) ? ub : 0.f;

    unsigned long long nz0 = (dob >= 0 && dob < 64) ? (1ull << dob) : 0ull;
    unsigned long long nz1 = (dob >= 64) ? (1ull << (dob - 64)) : 0ull;

    const int* ord = order + b * NN;
    const ulonglong2* bb = bitsT + (size_t)b * NN;

    const unsigned long long lanebit = 1ull << lane;
    const float fidx0 = __int_as_float(lane << 5);
    const float fidx1 = __int_as_float((lane + 64) << 5);

    // ---- prologue: set up step 0's entries + scalars ----
    int node0 = __builtin_amdgcn_readfirstlane(ord[0]);
    int node1 = __builtin_amdgcn_readfirstlane(ord[1]);
    const ulonglong2 vb0 = bb[node0];
    ulonglong2 vbn = bb[node1];

    unsigned long long bw0c = rfl64(vb0.x);
    unsigned long long bw1c = rfl64(vb0.y);
    int cnt4_c;
    {
        const unsigned long long m0 = nz0 & bw0c;
        const unsigned long long m1 = nz1 & bw1c;
        const int c0 = __popcll(m0);
        const int cnt = c0 + __popcll(m1);
        cnt4_c = (cnt + 3) & ~3;
        const int p0 = mbcnt64(m0);
        if (m0 & lanebit) entb[0][p0] = make_float2(out0, fidx0);
        const int p1 = c0 + mbcnt64(m1);
        if (m1 & lanebit) entb[0][p1] = make_float2(out1, fidx1);
        const int top = (cnt4_c <= 32) ? 32 : cnt4_c;
        const int pp = cnt + lane;
        if (pp < top) entb[0][pp] = make_float2(0.f, __int_as_float(0));
    }
    asm volatile("s_waitcnt lgkmcnt(0)" ::: "memory");
    float2 eA[16], eB[16];
#pragma unroll
    for (int i = 0; i < 16; ++i) eA[i] = entb[0][2 * i + half];

    const float* Wn0 = W1 + (size_t)node0 * ((NN + 1) * HH);
    float w2v  = W2[node0 * HH + j];
    float b1v  = b1[node0 * HH + j];
    float xv   = x[b * NN + node0];
    float b2v  = b2[node0];
    float w1xv = Wn0[NN * HH + j];
    float wfr  = 0.f;

    int pend_node = 0;
    float pend_val = 0.f;

    // ---- main loop, unrolled by 2 to rotate register sets without moves ----
    for (int t = 0; t < NN; t += 2) {
        STEP(t,     eA, eB, 0, 1)
        STEP(t + 1, eB, eA, 1, 0)
    }

    // apply final pending update (from step NN-1)
    if (dob != pend_node && lane == (pend_node & 63)) {
        if (pend_node < 64) out0 = pend_val; else out1 = pend_val;
    }

    out[b * NN + lane] = out0;
    out[b * NN + 64 + lane] = out1;
}

extern "C" void kernel_launch(void* const* d_in, const int* in_sizes, int n_in,
                              void* d_out, int out_size, void* d_ws, size_t ws_size,
                              hipStream_t stream) {
    const float* x   = (const float*)d_in[0];
    const float* A   = (const float*)d_in[1];
    const float* u   = (const float*)d_in[2];
    const float* W1  = (const float*)d_in[3];
    const float* b1  = (const float*)d_in[4];
    const float* W2  = (const float*)d_in[5];
    const float* b2  = (const float*)d_in[6];
    const int* order = (const int*)d_in[7];
    const int* dox   = (const int*)d_in[8];

    ulonglong2* bitsT = (ulonglong2*)d_ws;  // 4096*128*16 B = 8 MB

    pack_bits<<<(BB * 32) / 256, 256, 0, stream>>>(A, bitsT);
    cond_mlp<<<BB, 64, 0, stream>>>(x, u, W1, b1, W2, b2, order, dox,
                                    bitsT, (float*)d_out);
}